// Round 4
// baseline (135.188 us; speedup 1.0000x reference)
//
#include <hip/hip_runtime.h>
#include <math.h>

#define BB 4
#define TT 4096
#define CC 1024
#define HS 64
#define MM (BB*TT)   // 16384
#define KSPLIT 6

typedef __attribute__((ext_vector_type(8))) short short8;    // 8 bf16 (4 VGPR)
typedef __attribute__((ext_vector_type(4))) float f32x4;     // MFMA acc
typedef __attribute__((ext_vector_type(4))) unsigned short ushort4v;

__device__ __forceinline__ unsigned short f2bf(float f) {   // RNE fp32->bf16
    union { float f; unsigned u; } v; v.f = f;
    return (unsigned short)((v.u + 0x7fffu + ((v.u >> 16) & 1u)) >> 16);
}

// packed RNE fp32x2 -> bf16x2 (bit-identical to f2bf for finite values)
__device__ __forceinline__ unsigned cvt_pk_bf16(float lo, float hi) {
    unsigned r;
    asm("v_cvt_pk_bf16_f32 %0, %1, %2" : "=v"(r) : "v"(lo), "v"(hi));
    return r;
}

// async global->LDS DMA, 16B per lane; LDS dest = wave-uniform base + lane*16
typedef __attribute__((address_space(3))) unsigned short lds_us;
typedef __attribute__((address_space(1))) const unsigned short glb_us;
__device__ __forceinline__ void g2lds16(const unsigned short* g, unsigned short* l) {
    __builtin_amdgcn_global_load_lds((glb_us*)g, (lds_us*)l, 16, 0, 0);
}

// ---------------------------------------------------------------------------
// prep: Wt = W^T bf16, PRE-SWIZZLED + chunk-linearized for qkv's global_load_lds
// (unchanged from R3). Wq pre-scaled by 0.125.
// ---------------------------------------------------------------------------
__global__ __launch_bounds__(256) void prep_kernel(
    const float* __restrict__ Wq, const float* __restrict__ Wk,
    const float* __restrict__ Wv, unsigned short* __restrict__ Wt)
{
    const int which = blockIdx.x >> 4;
    const int k0 = (blockIdx.x & 15) * 64;
    const float* __restrict__ W = (which == 0) ? Wq : (which == 1) ? Wk : Wv;
    const float scale = (which == 0) ? 0.125f : 1.0f;
    __shared__ unsigned short lds[64][65];
    const int t = threadIdx.x;
    #pragma unroll
    for (int i = 0; i < 16; i++) {
        int idx = t + 256 * i;
        int r = idx >> 6, n = idx & 63;           // coalesced read (n fast)
        lds[r][n] = f2bf(W[(size_t)(k0 + r) * 64 + n] * scale);
    }
    __syncthreads();
    #pragma unroll
    for (int i = 0; i < 16; i++) {
        int idx = t + 256 * i;
        int n = idx >> 6, r = idx & 63;           // coalesced write (k fast)
        int nrow = which * 64 + n;
        int kg = k0 + r;
        int ck = kg >> 7, kloc = kg & 127;
        Wt[(size_t)ck * 24576 + (((nrow << 7) + kloc) ^ ((nrow & 7) << 3))] = lds[r][n];
    }
}

// ---------------------------------------------------------------------------
// qkv_mfma: as R3 (W via global_load_lds, swizzled; x reg-staged). Epilogue
// CHANGED: K and V are now emitted TILE-MAJOR + PRE-SWIZZLED for attn's
// global_load_lds staging:
//   kbt[b][kt][key][d]: short idx = (b*64+kt)*4096 + key*64 + (d ^ ((key&7)<<3))
//   vTt[b][kt][d][key]: short idx = (b*64+kt)*4096 + d*64 + (key ^ ((d&7)<<3))
// Each 64-key tile is one contiguous 8 KB block -> pure linear DMA in attn;
// the XOR pre-swizzle makes attn's strided b128 frag reads 2-way (free).
// ---------------------------------------------------------------------------
__global__ __launch_bounds__(256, 2) void qkv_mfma(
    const float* __restrict__ x, const unsigned short* __restrict__ Wt,
    unsigned short* __restrict__ qb, unsigned short* __restrict__ kbt,
    unsigned short* __restrict__ vTt)
{
    const int rt = blockIdx.x;                 // 32-row tile, 512 blocks
    __shared__ __align__(16) unsigned short xs[32][136];   // padded, reg-staged
    __shared__ __align__(16) unsigned short wsf[192 * 128]; // linear, DMA'd (48KB)

    const int t = threadIdx.x;
    const int w = t >> 6;
    const int lane = t & 63;
    const int quad = lane >> 4;
    const int c = lane & 15;

    const int c2x32 = ((c >> 2) & 1) << 5;     // swizzle: ks-bit flip (in shorts)
    const int quad2 = quad ^ (c & 3);          // swizzle: quad permute

    float4 xreg[4];
    #pragma unroll
    for (int i = 0; i < 4; i++) {              // chunk 0 x
        int idx = t + 256 * i;
        int r = idx >> 5, c4 = (idx & 31) * 4;
        xreg[i] = *(const float4*)(x + (size_t)(rt * 32 + r) * CC + c4);
    }

    f32x4 acc[2][3];
    #pragma unroll
    for (int mt = 0; mt < 2; mt++)
        #pragma unroll
        for (int j = 0; j < 3; j++) acc[mt][j] = (f32x4){0.f, 0.f, 0.f, 0.f};

    for (int ck = 0; ck < 8; ++ck) {
        __syncthreads();                       // prev compute done reading xs/wsf
        // W chunk: 12 x 4KB async DMA (48KB), linear dest, pre-swizzled source
        {
            const unsigned short* wgp = Wt + (size_t)ck * 24576 + t * 8;
            #pragma unroll
            for (int i = 0; i < 12; i++)
                g2lds16(wgp + i * 2048, wsf + (i * 256 + w * 64) * 8);
        }
        // stage x (from regs loaded during previous compute phase)
        #pragma unroll
        for (int i = 0; i < 4; i++) {
            int idx = t + 256 * i;
            int r = idx >> 5, c4 = (idx & 31) * 4;
            ushort4v p = { f2bf(xreg[i].x), f2bf(xreg[i].y), f2bf(xreg[i].z), f2bf(xreg[i].w) };
            *(ushort4v*)&xs[r][c4] = p;
        }
        __syncthreads();                       // drains W DMA + x ds-writes

        // next-chunk x load: issued at top of compute, drains at next barrier
        if (ck + 1 < 8) {
            #pragma unroll
            for (int i = 0; i < 4; i++) {
                int idx = t + 256 * i;
                int r = idx >> 5, c4 = (idx & 31) * 4;
                xreg[i] = *(const float4*)(x + (size_t)(rt * 32 + r) * CC + (ck + 1) * 128 + c4);
            }
        }

        #pragma unroll
        for (int ks = 0; ks < 4; ks++) {
            short8 af[2], bf[3];
            #pragma unroll
            for (int mt = 0; mt < 2; mt++)
                af[mt] = *(const short8*)&xs[16 * mt + c][ks * 32 + quad * 8];
            #pragma unroll
            for (int j = 0; j < 3; j++)
                bf[j] = *(const short8*)&wsf[(16 * (w + 4 * j) + c) * 128 +
                                             ((ks * 32) ^ c2x32) + quad2 * 8];
            #pragma unroll
            for (int mt = 0; mt < 2; mt++)
                #pragma unroll
                for (int j = 0; j < 3; j++)
                    acc[mt][j] = __builtin_amdgcn_mfma_f32_16x16x32_bf16(af[mt], bf[j], acc[mt][j], 0, 0, 0);
        }
    }

    // epilogue: q direct; k -> tiled+swizzled kbt; v -> LDS transpose -> vTt
    __syncthreads();
    const int b  = rt >> 7;                    // batch
    unsigned short (*vtb)[72] = (unsigned short (*)[72])wsf;  // [d 0..63][t-local 0..31]
    #pragma unroll
    for (int mt = 0; mt < 2; mt++) {
        int grow = rt * 32 + 16 * mt + quad * 4;
        #pragma unroll
        for (int reg = 0; reg < 4; reg++) {
            int trow = grow + reg;                     // global row
            qb[(size_t)trow * HS + 16 * w + c] = f2bf(acc[mt][0][reg]);
            int tin = trow & 4095;                     // row within batch
            int kt = tin >> 6, kl = tin & 63;
            int dcol = 16 * w + c;
            kbt[(size_t)(b * 64 + kt) * 4096 + kl * 64 + (dcol ^ ((kl & 7) << 3))]
                = f2bf(acc[mt][1][reg]);
            vtb[16 * w + c][16 * mt + quad * 4 + reg] = f2bf(acc[mt][2][reg]);
        }
    }
    __syncthreads();
    {
        const int t0 = (rt & 127) * 32;
        const int kt = t0 >> 6, half = (t0 >> 5) & 1;
        int d = t >> 2, c8 = (t & 3) * 8;
        short8 v0 = *(const short8*)&vtb[d][c8];
        *(short8*)(vTt + (size_t)(b * 64 + kt) * 4096 + d * 64 +
                   (((half * 32 + c8) ^ ((d & 7) << 3)))) = v0;
    }
}

// ---------------------------------------------------------------------------
// attn_mfma: causal flash attention, QT=128 (4 waves x 32 q), K-split 6.
// NEW STRUCTURE (T3 minimum 2-phase): K/V staged via global_load_lds into a
// DOUBLE-BUFFERED linear LDS region -- per tile: issue next tile's 4 linear
// 4KB DMAs, compute current tile, ONE __syncthreads() (its implicit vmcnt
// drain = the pipeline wait, after a full compute phase of overlap).
// Removes per tile: 1 barrier, 4 global->VGPR loads + 4 ds_write_b128/thread,
// and the vmcnt stall before staging stores. Tiles are pre-swizzled by qkv so
// the linear DMA yields 2-way (free) bank aliasing on all b128 frag reads.
// LDS 50.4 KB -> 3 blocks/CU (grid 768 = exactly 3/CU, 12 waves/CU).
// Fixed softmax shift (=0) -> additive partials; combine normalizes.
// ---------------------------------------------------------------------------
__global__ __launch_bounds__(256, 3) void attn_mfma(
    const unsigned short* __restrict__ qb, const unsigned short* __restrict__ kbt,
    const unsigned short* __restrict__ vTt, float* __restrict__ Opart,
    float* __restrict__ lpart)
{
    const int bid = blockIdx.x;                  // 768 = 32 qt x 6 j x 4 b
    const int qt  = (TT / 128 - 1) - bid / 24;   // descending q-tile
    const int rem = bid % 24;
    const int j   = rem >> 2;                    // K-split index 0..5
    const int b   = rem & 3;

    __shared__ __align__(16) unsigned short kv[2][2][4096]; // [buf][K/V][tile] 32 KB
    __shared__ unsigned short ps[4][32][72];                // per-wave P (padded)

    const int t = threadIdx.x;
    const int w = t >> 6;
    const int lane = t & 63;
    const int quad = lane >> 4;
    const int c = lane & 15;
    const int qrow = qt * 128 + 32 * w;        // wave's first query row

    // swizzled column offsets for frag reads (row&7 == c&7 for all frag rows)
    const int csw0 = (quad * 8) ^ ((c & 7) << 3);
    const int csw1 = (32 + quad * 8) ^ ((c & 7) << 3);

    // Q A-frags resident in registers: 2 m-frags x 2 ksteps
    short8 aq[2][2];
    #pragma unroll
    for (int mt = 0; mt < 2; mt++)
        #pragma unroll
        for (int kstep = 0; kstep < 2; kstep++)
            aq[mt][kstep] = *(const short8*)(qb + (size_t)(b * TT + qrow + 16 * mt + c) * HS + kstep * 32 + quad * 8);

    const int lastkt = 2 * qt + 1;             // last key-tile with any work
    const int nkt = (lastkt >= j) ? ((lastkt - j) / KSPLIT) + 1 : 0;
    const unsigned short* Ktiles = kbt + (size_t)b * 64 * 4096;
    const unsigned short* Vtiles = vTt + (size_t)b * 64 * 4096;

// 4 linear 4KB DMA strips: whole 8KB K-tile + 8KB V-tile into kv[BUF]
#define STAGE(BUF, KT) do { \
    size_t o_ = (size_t)(KT) * 4096 + t * 8; \
    g2lds16(Ktiles + o_,        &kv[BUF][0][w * 512]); \
    g2lds16(Ktiles + o_ + 2048, &kv[BUF][0][2048 + w * 512]); \
    g2lds16(Vtiles + o_,        &kv[BUF][1][w * 512]); \
    g2lds16(Vtiles + o_ + 2048, &kv[BUF][1][2048 + w * 512]); } while (0)

    float l[2][4] = {{0.f,0.f,0.f,0.f},{0.f,0.f,0.f,0.f}};
    f32x4 oacc[2][4];
    #pragma unroll
    for (int mt = 0; mt < 2; mt++)
        #pragma unroll
        for (int dt = 0; dt < 4; dt++) oacc[mt][dt] = (f32x4){0.f, 0.f, 0.f, 0.f};

// per-16-key-group score+exp+P-store; MASKC is the per-element keep predicate
#define SCORE_ST(CB, MASKC) do { \
    _Pragma("unroll") \
    for (int st = 0; st < 4; st++) { \
        f32x4 s[2]; \
        s[0] = (f32x4){0.f,0.f,0.f,0.f}; s[1] = (f32x4){0.f,0.f,0.f,0.f}; \
        { \
            short8 bf0 = *(const short8*)&kv[CB][0][(16 * st + c) * 64 + csw0]; \
            short8 bf1 = *(const short8*)&kv[CB][0][(16 * st + c) * 64 + csw1]; \
            s[0] = __builtin_amdgcn_mfma_f32_16x16x32_bf16(aq[0][0], bf0, s[0], 0, 0, 0); \
            s[1] = __builtin_amdgcn_mfma_f32_16x16x32_bf16(aq[1][0], bf0, s[1], 0, 0, 0); \
            s[0] = __builtin_amdgcn_mfma_f32_16x16x32_bf16(aq[0][1], bf1, s[0], 0, 0, 0); \
            s[1] = __builtin_amdgcn_mfma_f32_16x16x32_bf16(aq[1][1], bf1, s[1], 0, 0, 0); \
        } \
        _Pragma("unroll") \
        for (int mt = 0; mt < 2; mt++) { \
            _Pragma("unroll") \
            for (int reg = 0; reg < 4; reg++) { \
                int kg = kt0 + 16 * st + c; (void)kg; \
                int qg = qrow + 16 * mt + quad * 4 + reg; (void)qg; \
                float p = (MASKC) ? __expf(s[mt][reg]) : 0.f; \
                s[mt][reg] = p; \
                l[mt][reg] += p; \
            } \
            unsigned p01 = cvt_pk_bf16(s[mt][0], s[mt][1]); \
            unsigned p23 = cvt_pk_bf16(s[mt][2], s[mt][3]); \
            ps[w][16 * mt + quad * 4 + 0][16 * st + c] = (unsigned short)p01; \
            ps[w][16 * mt + quad * 4 + 1][16 * st + c] = (unsigned short)(p01 >> 16); \
            ps[w][16 * mt + quad * 4 + 2][16 * st + c] = (unsigned short)p23; \
            ps[w][16 * mt + quad * 4 + 3][16 * st + c] = (unsigned short)(p23 >> 16); \
        } \
    } } while (0)

    if (nkt > 0) STAGE(0, j);
    __syncthreads();                             // tile 0 staged

    for (int i = 0; i < nkt; i++) {
        const int cb = i & 1;
        const int kt = j + KSPLIT * i;
        const int kt0 = kt * 64;

        // issue next tile's DMA FIRST (overlaps this tile's compute)
        if (i + 1 < nkt) STAGE(cb ^ 1, kt + KSPLIT);

        // wave-uniform skip: tile entirely above this wave's diagonal
        if (kt0 <= qrow + 31) {
            if (kt >= 2 * qt) {
                SCORE_ST(cb, kg <= qg);          // diagonal-adjacent: mask
            } else {
                SCORE_ST(cb, 1);                 // interior: no mask
            }

            // ---- PV accumulate (unnormalized); B-frags reused across m-frags
            #pragma unroll
            for (int kstep = 0; kstep < 2; kstep++) {
                const int csw = kstep ? csw1 : csw0;
                short8 ap[2];
                #pragma unroll
                for (int mt = 0; mt < 2; mt++)
                    ap[mt] = *(const short8*)&ps[w][16 * mt + c][kstep * 32 + quad * 8];
                #pragma unroll
                for (int dt = 0; dt < 4; dt++) {
                    short8 bv = *(const short8*)&kv[cb][1][(16 * dt + c) * 64 + csw];
                    oacc[0][dt] = __builtin_amdgcn_mfma_f32_16x16x32_bf16(ap[0], bv, oacc[0][dt], 0, 0, 0);
                    oacc[1][dt] = __builtin_amdgcn_mfma_f32_16x16x32_bf16(ap[1], bv, oacc[1][dt], 0, 0, 0);
                }
            }
        }

        __syncthreads();   // ONE barrier/tile: drains DMA, closes compute
    }
#undef SCORE_ST
#undef STAGE

    // ---- epilogue: reduce l over 16 key-lanes, write unnormalized partials
    #pragma unroll
    for (int mt = 0; mt < 2; mt++)
        #pragma unroll
        for (int reg = 0; reg < 4; reg++)
            #pragma unroll
            for (int msk = 1; msk < 16; msk <<= 1)
                l[mt][reg] += __shfl_xor(l[mt][reg], msk);

    float* __restrict__ Oj = Opart + (size_t)j * MM * HS;
    #pragma unroll
    for (int mt = 0; mt < 2; mt++)
        #pragma unroll
        for (int dt = 0; dt < 4; dt++)
            #pragma unroll
            for (int reg = 0; reg < 4; reg++)
                Oj[(size_t)(b * TT + qrow + 16 * mt + quad * 4 + reg) * HS + 16 * dt + c] = oacc[mt][dt][reg];
    if (c == 0)
        #pragma unroll
        for (int mt = 0; mt < 2; mt++)
            #pragma unroll
            for (int reg = 0; reg < 4; reg++)
                lpart[(size_t)j * MM + b * TT + qrow + 16 * mt + quad * 4 + reg] = l[mt][reg];
}

// ---------------------------------------------------------------------------
// combine: out = (sum_j O_j) / (sum_j l_j), j=0..5. 262144 float4s, grid 1024.
// ---------------------------------------------------------------------------
__global__ __launch_bounds__(256) void combine_kernel(
    const float* __restrict__ Opart, const float* __restrict__ lpart,
    float* __restrict__ out)
{
    const int id = blockIdx.x * 256 + threadIdx.x;   // 0 .. MM*HS/4-1
    const int row = id >> 4;
    float l = 0.f;
    #pragma unroll
    for (int j = 0; j < KSPLIT; j++) l += lpart[(size_t)j * MM + row];
    const float4* O = (const float4*)Opart;
    const size_t stride = (size_t)MM * HS / 4;
    float4 r = {0.f, 0.f, 0.f, 0.f};
    #pragma unroll
    for (int j = 0; j < KSPLIT; j++) {
        float4 a = O[id + (size_t)j * stride];
        r.x += a.x; r.y += a.y; r.z += a.z; r.w += a.w;
    }
    float inv = 1.f / l;
    r.x *= inv; r.y *= inv; r.z *= inv; r.w *= inv;
    ((float4*)out)[id] = r;
}

extern "C" void kernel_launch(void* const* d_in, const int* in_sizes, int n_in,
                              void* d_out, int out_size, void* d_ws, size_t ws_size,
                              hipStream_t stream) {
    const float* x  = (const float*)d_in[0];
    const float* Wq = (const float*)d_in[1];
    const float* Wk = (const float*)d_in[2];
    const float* Wv = (const float*)d_in[3];
    float* out = (float*)d_out;

    unsigned short* Wt   = (unsigned short*)d_ws;            // 384 KB (swizzled)
    unsigned short* qbuf = Wt + 3 * 64 * 1024;               // 2 MB each
    unsigned short* kbt  = qbuf + (size_t)MM * HS;           // tiled+swizzled K
    unsigned short* vTt  = kbt + (size_t)MM * HS;            // tiled+swizzled V^T
    float* Opart = (float*)(vTt + (size_t)MM * HS);          // 6 x 4 MB
    float* lpart = Opart + (size_t)KSPLIT * MM * HS;         // 384 KB

    prep_kernel<<<48, 256, 0, stream>>>(Wq, Wk, Wv, Wt);
    qkv_mfma<<<MM / 32, 256, 0, stream>>>(x, Wt, qbuf, kbt, vTt);
    attn_mfma<<<BB * (TT / 128) * KSPLIT, 256, 0, stream>>>(qbuf, kbt, vTt, Opart, lpart);
    combine_kernel<<<1024, 256, 0, stream>>>(Opart, lpart, out);
}

// Round 5
// 133.867 us; speedup vs baseline: 1.0099x; 1.0099x over previous
//
#include <hip/hip_runtime.h>
#include <math.h>

#define BB 4
#define TT 4096
#define CC 1024
#define HS 64
#define MM (BB*TT)   // 16384
#define KSPLIT 8

typedef __attribute__((ext_vector_type(8))) short short8;    // 8 bf16 (4 VGPR)
typedef __attribute__((ext_vector_type(4))) float f32x4;     // MFMA acc
typedef __attribute__((ext_vector_type(4))) unsigned short ushort4v;

__device__ __forceinline__ unsigned short f2bf(float f) {   // RNE fp32->bf16
    union { float f; unsigned u; } v; v.f = f;
    return (unsigned short)((v.u + 0x7fffu + ((v.u >> 16) & 1u)) >> 16);
}

// packed RNE fp32x2 -> bf16x2 (bit-identical to f2bf for finite values)
__device__ __forceinline__ unsigned cvt_pk_bf16(float lo, float hi) {
    unsigned r;
    asm("v_cvt_pk_bf16_f32 %0, %1, %2" : "=v"(r) : "v"(lo), "v"(hi));
    return r;
}

// async global->LDS DMA, 16B per lane; LDS dest = wave-uniform base + lane*16
typedef __attribute__((address_space(3))) unsigned short lds_us;
typedef __attribute__((address_space(1))) const unsigned short glb_us;
__device__ __forceinline__ void g2lds16(const unsigned short* g, unsigned short* l) {
    __builtin_amdgcn_global_load_lds((glb_us*)g, (lds_us*)l, 16, 0, 0);
}

// ---------------------------------------------------------------------------
// prep: Wt = W^T bf16, PRE-SWIZZLED + chunk-linearized for qkv's global_load_lds
// (unchanged from R3). Wq pre-scaled by 0.125.
// ---------------------------------------------------------------------------
__global__ __launch_bounds__(256) void prep_kernel(
    const float* __restrict__ Wq, const float* __restrict__ Wk,
    const float* __restrict__ Wv, unsigned short* __restrict__ Wt)
{
    const int which = blockIdx.x >> 4;
    const int k0 = (blockIdx.x & 15) * 64;
    const float* __restrict__ W = (which == 0) ? Wq : (which == 1) ? Wk : Wv;
    const float scale = (which == 0) ? 0.125f : 1.0f;
    __shared__ unsigned short lds[64][65];
    const int t = threadIdx.x;
    #pragma unroll
    for (int i = 0; i < 16; i++) {
        int idx = t + 256 * i;
        int r = idx >> 6, n = idx & 63;           // coalesced read (n fast)
        lds[r][n] = f2bf(W[(size_t)(k0 + r) * 64 + n] * scale);
    }
    __syncthreads();
    #pragma unroll
    for (int i = 0; i < 16; i++) {
        int idx = t + 256 * i;
        int n = idx >> 6, r = idx & 63;           // coalesced write (k fast)
        int nrow = which * 64 + n;
        int kg = k0 + r;
        int ck = kg >> 7, kloc = kg & 127;
        Wt[(size_t)ck * 24576 + (((nrow << 7) + kloc) ^ ((nrow & 7) << 3))] = lds[r][n];
    }
}

// ---------------------------------------------------------------------------
// qkv_mfma: unchanged from R4 (W via global_load_lds, swizzled; x reg-staged;
// K/V emitted tile-major + pre-swizzled for attn's DMA staging).
// ---------------------------------------------------------------------------
__global__ __launch_bounds__(256, 2) void qkv_mfma(
    const float* __restrict__ x, const unsigned short* __restrict__ Wt,
    unsigned short* __restrict__ qb, unsigned short* __restrict__ kbt,
    unsigned short* __restrict__ vTt)
{
    const int rt = blockIdx.x;                 // 32-row tile, 512 blocks
    __shared__ __align__(16) unsigned short xs[32][136];   // padded, reg-staged
    __shared__ __align__(16) unsigned short wsf[192 * 128]; // linear, DMA'd (48KB)

    const int t = threadIdx.x;
    const int w = t >> 6;
    const int lane = t & 63;
    const int quad = lane >> 4;
    const int c = lane & 15;

    const int c2x32 = ((c >> 2) & 1) << 5;     // swizzle: ks-bit flip (in shorts)
    const int quad2 = quad ^ (c & 3);          // swizzle: quad permute

    float4 xreg[4];
    #pragma unroll
    for (int i = 0; i < 4; i++) {              // chunk 0 x
        int idx = t + 256 * i;
        int r = idx >> 5, c4 = (idx & 31) * 4;
        xreg[i] = *(const float4*)(x + (size_t)(rt * 32 + r) * CC + c4);
    }

    f32x4 acc[2][3];
    #pragma unroll
    for (int mt = 0; mt < 2; mt++)
        #pragma unroll
        for (int j = 0; j < 3; j++) acc[mt][j] = (f32x4){0.f, 0.f, 0.f, 0.f};

    for (int ck = 0; ck < 8; ++ck) {
        __syncthreads();                       // prev compute done reading xs/wsf
        // W chunk: 12 x 4KB async DMA (48KB), linear dest, pre-swizzled source
        {
            const unsigned short* wgp = Wt + (size_t)ck * 24576 + t * 8;
            #pragma unroll
            for (int i = 0; i < 12; i++)
                g2lds16(wgp + i * 2048, wsf + (i * 256 + w * 64) * 8);
        }
        // stage x (from regs loaded during previous compute phase)
        #pragma unroll
        for (int i = 0; i < 4; i++) {
            int idx = t + 256 * i;
            int r = idx >> 5, c4 = (idx & 31) * 4;
            ushort4v p = { f2bf(xreg[i].x), f2bf(xreg[i].y), f2bf(xreg[i].z), f2bf(xreg[i].w) };
            *(ushort4v*)&xs[r][c4] = p;
        }
        __syncthreads();                       // drains W DMA + x ds-writes

        // next-chunk x load: issued at top of compute, drains at next barrier
        if (ck + 1 < 8) {
            #pragma unroll
            for (int i = 0; i < 4; i++) {
                int idx = t + 256 * i;
                int r = idx >> 5, c4 = (idx & 31) * 4;
                xreg[i] = *(const float4*)(x + (size_t)(rt * 32 + r) * CC + (ck + 1) * 128 + c4);
            }
        }

        #pragma unroll
        for (int ks = 0; ks < 4; ks++) {
            short8 af[2], bf[3];
            #pragma unroll
            for (int mt = 0; mt < 2; mt++)
                af[mt] = *(const short8*)&xs[16 * mt + c][ks * 32 + quad * 8];
            #pragma unroll
            for (int j = 0; j < 3; j++)
                bf[j] = *(const short8*)&wsf[(16 * (w + 4 * j) + c) * 128 +
                                             ((ks * 32) ^ c2x32) + quad2 * 8];
            #pragma unroll
            for (int mt = 0; mt < 2; mt++)
                #pragma unroll
                for (int j = 0; j < 3; j++)
                    acc[mt][j] = __builtin_amdgcn_mfma_f32_16x16x32_bf16(af[mt], bf[j], acc[mt][j], 0, 0, 0);
        }
    }

    // epilogue: q direct; k -> tiled+swizzled kbt; v -> LDS transpose -> vTt
    __syncthreads();
    const int b  = rt >> 7;                    // batch
    unsigned short (*vtb)[72] = (unsigned short (*)[72])wsf;  // [d 0..63][t-local 0..31]
    #pragma unroll
    for (int mt = 0; mt < 2; mt++) {
        int grow = rt * 32 + 16 * mt + quad * 4;
        #pragma unroll
        for (int reg = 0; reg < 4; reg++) {
            int trow = grow + reg;                     // global row
            qb[(size_t)trow * HS + 16 * w + c] = f2bf(acc[mt][0][reg]);
            int tin = trow & 4095;                     // row within batch
            int kt = tin >> 6, kl = tin & 63;
            int dcol = 16 * w + c;
            kbt[(size_t)(b * 64 + kt) * 4096 + kl * 64 + (dcol ^ ((kl & 7) << 3))]
                = f2bf(acc[mt][1][reg]);
            vtb[16 * w + c][16 * mt + quad * 4 + reg] = f2bf(acc[mt][2][reg]);
        }
    }
    __syncthreads();
    {
        const int t0 = (rt & 127) * 32;
        const int kt = t0 >> 6, half = (t0 >> 5) & 1;
        int d = t >> 2, c8 = (t & 3) * 8;
        short8 v0 = *(const short8*)&vtb[d][c8];
        *(short8*)(vTt + (size_t)(b * 64 + kt) * 4096 + d * 64 +
                   (((half * 32 + c8) ^ ((d & 7) << 3)))) = v0;
    }
}

// ---------------------------------------------------------------------------
// attn_mfma: causal flash attention, QT=128 (4 waves x 32 q), K-split 8.
// LOAD BALANCE (the R5 lever): grid 1024 at 3 blocks/CU occupancy = 768
// statically resident + 256 backfill. Dispatch-order -> qt remap makes the 3
// resident slots' qt-sums near-constant per CU (slot0 31..24 desc, slot1
// 16..23 ASC, slot2 15..8 desc, backfill 7..0 desc = smallest last, LPT):
// CU work spread drops from ~45..69 to ~55..62 qt-units + backfill evens out.
// Previously (all R1-R4 variants) static assignment gave ~1.5:1 CU imbalance,
// which explains why per-tile structure changes never moved total time.
// s_setprio(1) wraps MFMA clusters (desynced independent blocks = m191 regime).
// Staging: single-barrier double-buffered global_load_lds (R4 structure).
// ---------------------------------------------------------------------------
__global__ __launch_bounds__(256, 3) void attn_mfma(
    const unsigned short* __restrict__ qb, const unsigned short* __restrict__ kbt,
    const unsigned short* __restrict__ vTt, float* __restrict__ Opart,
    float* __restrict__ lpart)
{
    const int bid = blockIdx.x;                  // 1024 = 32 p x 8 j x 4 b
    const int p   = bid >> 5;                    // dispatch-order qt-group
    const int qt  = (p >= 8 && p < 16) ? (p + 8) : (31 - p);  // balanced map
    const int rem = bid & 31;
    const int j   = rem >> 2;                    // K-split index 0..7
    const int b   = rem & 3;

    __shared__ __align__(16) unsigned short kv[2][2][4096]; // [buf][K/V][tile] 32 KB
    __shared__ unsigned short ps[4][32][72];                // per-wave P (padded)

    const int t = threadIdx.x;
    const int w = t >> 6;
    const int lane = t & 63;
    const int quad = lane >> 4;
    const int c = lane & 15;
    const int qrow = qt * 128 + 32 * w;        // wave's first query row

    // swizzled column offsets for frag reads (row&7 == c&7 for all frag rows)
    const int csw0 = (quad * 8) ^ ((c & 7) << 3);
    const int csw1 = (32 + quad * 8) ^ ((c & 7) << 3);

    // Q A-frags resident in registers: 2 m-frags x 2 ksteps
    short8 aq[2][2];
    #pragma unroll
    for (int mt = 0; mt < 2; mt++)
        #pragma unroll
        for (int kstep = 0; kstep < 2; kstep++)
            aq[mt][kstep] = *(const short8*)(qb + (size_t)(b * TT + qrow + 16 * mt + c) * HS + kstep * 32 + quad * 8);

    const int lastkt = 2 * qt + 1;             // last key-tile with any work
    const int nkt = (lastkt >= j) ? ((lastkt - j) / KSPLIT) + 1 : 0;
    const unsigned short* Ktiles = kbt + (size_t)b * 64 * 4096;
    const unsigned short* Vtiles = vTt + (size_t)b * 64 * 4096;

// 4 linear 4KB DMA strips: whole 8KB K-tile + 8KB V-tile into kv[BUF]
#define STAGE(BUF, KT) do { \
    size_t o_ = (size_t)(KT) * 4096 + t * 8; \
    g2lds16(Ktiles + o_,        &kv[BUF][0][w * 512]); \
    g2lds16(Ktiles + o_ + 2048, &kv[BUF][0][2048 + w * 512]); \
    g2lds16(Vtiles + o_,        &kv[BUF][1][w * 512]); \
    g2lds16(Vtiles + o_ + 2048, &kv[BUF][1][2048 + w * 512]); } while (0)

    float l[2][4] = {{0.f,0.f,0.f,0.f},{0.f,0.f,0.f,0.f}};
    f32x4 oacc[2][4];
    #pragma unroll
    for (int mt = 0; mt < 2; mt++)
        #pragma unroll
        for (int dt = 0; dt < 4; dt++) oacc[mt][dt] = (f32x4){0.f, 0.f, 0.f, 0.f};

// per-16-key-group score+exp+P-store; MASKC is the per-element keep predicate
#define SCORE_ST(CB, MASKC) do { \
    _Pragma("unroll") \
    for (int st = 0; st < 4; st++) { \
        f32x4 s[2]; \
        s[0] = (f32x4){0.f,0.f,0.f,0.f}; s[1] = (f32x4){0.f,0.f,0.f,0.f}; \
        { \
            short8 bf0 = *(const short8*)&kv[CB][0][(16 * st + c) * 64 + csw0]; \
            short8 bf1 = *(const short8*)&kv[CB][0][(16 * st + c) * 64 + csw1]; \
            __builtin_amdgcn_s_setprio(1); \
            s[0] = __builtin_amdgcn_mfma_f32_16x16x32_bf16(aq[0][0], bf0, s[0], 0, 0, 0); \
            s[1] = __builtin_amdgcn_mfma_f32_16x16x32_bf16(aq[1][0], bf0, s[1], 0, 0, 0); \
            s[0] = __builtin_amdgcn_mfma_f32_16x16x32_bf16(aq[0][1], bf1, s[0], 0, 0, 0); \
            s[1] = __builtin_amdgcn_mfma_f32_16x16x32_bf16(aq[1][1], bf1, s[1], 0, 0, 0); \
            __builtin_amdgcn_s_setprio(0); \
        } \
        _Pragma("unroll") \
        for (int mt = 0; mt < 2; mt++) { \
            _Pragma("unroll") \
            for (int reg = 0; reg < 4; reg++) { \
                int kg = kt0 + 16 * st + c; (void)kg; \
                int qg = qrow + 16 * mt + quad * 4 + reg; (void)qg; \
                float p_ = (MASKC) ? __expf(s[mt][reg]) : 0.f; \
                s[mt][reg] = p_; \
                l[mt][reg] += p_; \
            } \
            unsigned p01 = cvt_pk_bf16(s[mt][0], s[mt][1]); \
            unsigned p23 = cvt_pk_bf16(s[mt][2], s[mt][3]); \
            ps[w][16 * mt + quad * 4 + 0][16 * st + c] = (unsigned short)p01; \
            ps[w][16 * mt + quad * 4 + 1][16 * st + c] = (unsigned short)(p01 >> 16); \
            ps[w][16 * mt + quad * 4 + 2][16 * st + c] = (unsigned short)p23; \
            ps[w][16 * mt + quad * 4 + 3][16 * st + c] = (unsigned short)(p23 >> 16); \
        } \
    } } while (0)

    if (nkt > 0) STAGE(0, j);
    __syncthreads();                             // tile 0 staged

    for (int i = 0; i < nkt; i++) {
        const int cb = i & 1;
        const int kt = j + KSPLIT * i;
        const int kt0 = kt * 64;

        // issue next tile's DMA FIRST (overlaps this tile's compute)
        if (i + 1 < nkt) STAGE(cb ^ 1, kt + KSPLIT);

        // wave-uniform skip: tile entirely above this wave's diagonal
        if (kt0 <= qrow + 31) {
            if (kt >= 2 * qt) {
                SCORE_ST(cb, kg <= qg);          // diagonal-adjacent: mask
            } else {
                SCORE_ST(cb, 1);                 // interior: no mask
            }

            // ---- PV accumulate (unnormalized); B-frags reused across m-frags
            __builtin_amdgcn_s_setprio(1);
            #pragma unroll
            for (int kstep = 0; kstep < 2; kstep++) {
                const int csw = kstep ? csw1 : csw0;
                short8 ap[2];
                #pragma unroll
                for (int mt = 0; mt < 2; mt++)
                    ap[mt] = *(const short8*)&ps[w][16 * mt + c][kstep * 32 + quad * 8];
                #pragma unroll
                for (int dt = 0; dt < 4; dt++) {
                    short8 bv = *(const short8*)&kv[cb][1][(16 * dt + c) * 64 + csw];
                    oacc[0][dt] = __builtin_amdgcn_mfma_f32_16x16x32_bf16(ap[0], bv, oacc[0][dt], 0, 0, 0);
                    oacc[1][dt] = __builtin_amdgcn_mfma_f32_16x16x32_bf16(ap[1], bv, oacc[1][dt], 0, 0, 0);
                }
            }
            __builtin_amdgcn_s_setprio(0);
        }

        __syncthreads();   // ONE barrier/tile: drains DMA, closes compute
    }
#undef SCORE_ST
#undef STAGE

    // ---- epilogue: reduce l over 16 key-lanes, write unnormalized partials
    #pragma unroll
    for (int mt = 0; mt < 2; mt++)
        #pragma unroll
        for (int reg = 0; reg < 4; reg++)
            #pragma unroll
            for (int msk = 1; msk < 16; msk <<= 1)
                l[mt][reg] += __shfl_xor(l[mt][reg], msk);

    float* __restrict__ Oj = Opart + (size_t)j * MM * HS;
    #pragma unroll
    for (int mt = 0; mt < 2; mt++)
        #pragma unroll
        for (int dt = 0; dt < 4; dt++)
            #pragma unroll
            for (int reg = 0; reg < 4; reg++)
                Oj[(size_t)(b * TT + qrow + 16 * mt + quad * 4 + reg) * HS + 16 * dt + c] = oacc[mt][dt][reg];
    if (c == 0)
        #pragma unroll
        for (int mt = 0; mt < 2; mt++)
            #pragma unroll
            for (int reg = 0; reg < 4; reg++)
                lpart[(size_t)j * MM + b * TT + qrow + 16 * mt + quad * 4 + reg] = l[mt][reg];
}

// ---------------------------------------------------------------------------
// combine: out = (sum_j O_j) / (sum_j l_j), j=0..7. 262144 float4s, grid 1024.
// ---------------------------------------------------------------------------
__global__ __launch_bounds__(256) void combine_kernel(
    const float* __restrict__ Opart, const float* __restrict__ lpart,
    float* __restrict__ out)
{
    const int id = blockIdx.x * 256 + threadIdx.x;   // 0 .. MM*HS/4-1
    const int row = id >> 4;
    float l = 0.f;
    #pragma unroll
    for (int j = 0; j < KSPLIT; j++) l += lpart[(size_t)j * MM + row];
    const float4* O = (const float4*)Opart;
    const size_t stride = (size_t)MM * HS / 4;
    float4 r = {0.f, 0.f, 0.f, 0.f};
    #pragma unroll
    for (int j = 0; j < KSPLIT; j++) {
        float4 a = O[id + (size_t)j * stride];
        r.x += a.x; r.y += a.y; r.z += a.z; r.w += a.w;
    }
    float inv = 1.f / l;
    r.x *= inv; r.y *= inv; r.z *= inv; r.w *= inv;
    ((float4*)out)[id] = r;
}

extern "C" void kernel_launch(void* const* d_in, const int* in_sizes, int n_in,
                              void* d_out, int out_size, void* d_ws, size_t ws_size,
                              hipStream_t stream) {
    const float* x  = (const float*)d_in[0];
    const float* Wq = (const float*)d_in[1];
    const float* Wk = (const float*)d_in[2];
    const float* Wv = (const float*)d_in[3];
    float* out = (float*)d_out;

    unsigned short* Wt   = (unsigned short*)d_ws;            // 384 KB (swizzled)
    unsigned short* qbuf = Wt + 3 * 64 * 1024;               // 2 MB each
    unsigned short* kbt  = qbuf + (size_t)MM * HS;           // tiled+swizzled K
    unsigned short* vTt  = kbt + (size_t)MM * HS;            // tiled+swizzled V^T
    float* Opart = (float*)(vTt + (size_t)MM * HS);          // 8 x 4 MB
    float* lpart = Opart + (size_t)KSPLIT * MM * HS;         // 512 KB

    prep_kernel<<<48, 256, 0, stream>>>(Wq, Wk, Wv, Wt);
    qkv_mfma<<<MM / 32, 256, 0, stream>>>(x, Wt, qbuf, kbt, vTt);
    attn_mfma<<<BB * (TT / 128) * KSPLIT, 256, 0, stream>>>(qbuf, kbt, vTt, Opart, lpart);
    combine_kernel<<<1024, 256, 0, stream>>>(Opart, lpart, out);
}